// Round 13
// baseline (372.633 us; speedup 1.0000x reference)
//
#include <hip/hip_runtime.h>
#include <hip/hip_cooperative_groups.h>

namespace cg = cooperative_groups;

#define NN 100000
#define SE 16
#define NE 1600000        // NN*SE
#define BB 4096
#define CAP 64            // per-node bucket capacity (deg ~ Poisson(16))
#define NMMB 1563         // ceil(NN/64) mm tiles
#define NLIST 20480       // 5*BB upper bound on needed nodes
#define BMW 3136          // bitmap words (ceil(NN/32)=3125, padded)

__device__ __forceinline__ float leaky(float x) { return x > 0.0f ? x : 0.2f * x; }

__device__ __forceinline__ unsigned short f2bf(float f) {     // RNE f32 -> bf16
    unsigned u = __float_as_uint(f);
    u += 0x7fffu + ((u >> 16) & 1u);
    return (unsigned short)(u >> 16);
}
__device__ __forceinline__ float bf2f(unsigned short h) {
    return __uint_as_float(((unsigned)h) << 16);
}
__device__ __forceinline__ float4 cvt4(ushort4 v) {
    float4 r;
    r.x = bf2f(v.x); r.y = bf2f(v.y); r.z = bf2f(v.z); r.w = bf2f(v.w);
    return r;
}

#define FMA4(a, sx, wv) \
    a.x = fmaf(sx, wv.x, a.x); a.y = fmaf(sx, wv.y, a.y); \
    a.z = fmaf(sx, wv.z, a.z); a.w = fmaf(sx, wv.w, a.w);

// One cooperative kernel, 5 phases separated by grid.sync():
//   P0 zero(bitmap,listlen,out[2BB]) -> P1 mark -> P2 mm + bucket (independent,
//   overlapped on the same CUs) -> P3 gather-softmax over needed list -> P4 score.
// __threadfence() around each sync: agent-scope release/acquire handles the
// non-coherent per-XCD L2s (Guideline 16). No early returns before last sync.
__global__ __launch_bounds__(256) void k_mega(
    const float4* __restrict__ X4, const float4* __restrict__ W4,
    const float* __restrict__ att, const float* __restrict__ bias,
    const int* __restrict__ edges,
    const int* __restrict__ user, const int* __restrict__ pos,
    const int* __restrict__ neg, const int* __restrict__ posr,
    const int* __restrict__ negr,
    ushort4* __restrict__ hb, float* __restrict__ s, float* __restrict__ t,
    int* __restrict__ cnt, unsigned* __restrict__ bitmap,
    int* __restrict__ listlen, int* __restrict__ list,
    int* __restrict__ esrc, float4* __restrict__ g4, float* __restrict__ out)
{
    cg::grid_group grid = cg::this_grid();
    __shared__ float4 Wl[64][16];    // W[k][4q..4q+3]
    __shared__ float4 xr[64][17];    // staged X rows, padded (2-way conflict = free)

    const int tid  = threadIdx.x;
    const int bid  = blockIdx.x;
    const int nb   = gridDim.x;
    const int nthr = nb * 256;
    const int gthr = bid * 256 + tid;
    const int lane = tid & 63;
    const int w    = tid >> 6;
    const int q    = lane & 15;
    const int sub  = lane >> 4;

    // ---------------- P0: zero small state ----------------
    for (int i = gthr; i < BMW; i += nthr) bitmap[i] = 0u;
    if (gthr == 0) { *listlen = 0; out[2 * BB] = 0.0f; }
    __threadfence();
    grid.sync();
    __threadfence();

    // ---------------- P1: mark needed nodes, lazy-zero cnt ----------------
    for (int i = gthr; i < NLIST; i += nthr) {
        int a = i >> 12, e = i & 4095;
        const int* arr = (a == 0) ? user : (a == 1) ? pos : (a == 2) ? neg
                       : (a == 3) ? posr : negr;
        int node = arr[e];
        unsigned bit = 1u << (node & 31);
        unsigned old = atomicOr(&bitmap[node >> 5], bit);
        if (!(old & bit)) {
            cnt[node] = 0;
            int p = atomicAdd(listlen, 1);
            list[p] = node;
        }
    }
    __threadfence();
    grid.sync();
    __threadfence();

    // ---------------- P2a: h = X@W (bf16) + s,t ----------------
    const int slot = (w << 2) | sub;     // 0..15
    for (int idx = tid; idx < 1024; idx += 256)
        Wl[idx >> 4][idx & 15] = W4[idx];
    const float4 ai = ((const float4*)att)[q];
    const float4 aj = ((const float4*)att)[16 + q];

    for (int tile = bid; tile < NMMB; tile += nb) {
        const int r0 = tile * 64;
        __syncthreads();
#pragma unroll
        for (int u = 0; u < 4; ++u) {
            int idx = u * 256 + tid;
            int row = r0 + (idx >> 4);
            xr[idx >> 4][idx & 15] = (row < NN) ? X4[(size_t)row * 16 + (idx & 15)]
                                                : make_float4(0.f, 0.f, 0.f, 0.f);
        }
        __syncthreads();

        const int rbase = slot * 4;
        float4 acc0 = {0,0,0,0}, acc1 = {0,0,0,0}, acc2 = {0,0,0,0}, acc3 = {0,0,0,0};
#pragma unroll 2
        for (int k4 = 0; k4 < 16; ++k4) {
            float4 w0 = Wl[k4 * 4 + 0][q];
            float4 w1 = Wl[k4 * 4 + 1][q];
            float4 w2 = Wl[k4 * 4 + 2][q];
            float4 w3 = Wl[k4 * 4 + 3][q];
            float4 x0 = xr[rbase + 0][k4];
            float4 x1 = xr[rbase + 1][k4];
            float4 x2 = xr[rbase + 2][k4];
            float4 x3 = xr[rbase + 3][k4];
            FMA4(acc0, x0.x, w0) FMA4(acc0, x0.y, w1) FMA4(acc0, x0.z, w2) FMA4(acc0, x0.w, w3)
            FMA4(acc1, x1.x, w0) FMA4(acc1, x1.y, w1) FMA4(acc1, x1.z, w2) FMA4(acc1, x1.w, w3)
            FMA4(acc2, x2.x, w0) FMA4(acc2, x2.y, w1) FMA4(acc2, x2.z, w2) FMA4(acc2, x2.w, w3)
            FMA4(acc3, x3.x, w0) FMA4(acc3, x3.y, w1) FMA4(acc3, x3.z, w2) FMA4(acc3, x3.w, w3)
        }

        float4 accs[4] = {acc0, acc1, acc2, acc3};
#pragma unroll
        for (int rr = 0; rr < 4; ++rr) {
            int row = r0 + rbase + rr;
            if (row >= NN) continue;
            float4 a = accs[rr];
            ushort4 hv;
            hv.x = f2bf(a.x); hv.y = f2bf(a.y); hv.z = f2bf(a.z); hv.w = f2bf(a.w);
            hb[(size_t)row * 16 + q] = hv;
            float ps = a.x * ai.x + a.y * ai.y + a.z * ai.z + a.w * ai.w;
            float pt = a.x * aj.x + a.y * aj.y + a.z * aj.z + a.w * aj.w;
#pragma unroll
            for (int off = 1; off < 16; off <<= 1) {
                ps += __shfl_xor(ps, off);
                pt += __shfl_xor(pt, off);
            }
            if (q == 0) { s[row] = ps; t[row] = pt; }
        }
    }

    // ---------------- P2b: dst-filtered edge bucket build ----------------
    for (int e = gthr; e < NE; e += nthr) {
        int j = __builtin_nontemporal_load(&edges[e]);
        int i = e >> 4;
        if (j != i && ((bitmap[j >> 5] >> (j & 31)) & 1u)) {
            int p = atomicAdd(&cnt[j], 1);
            if (p < CAP) esrc[j * CAP + p] = i;
        }
    }
    __threadfence();
    grid.sync();
    __threadfence();

    // ---------------- P3: gather-softmax-aggregate over needed list ----------------
    const int llen = *listlen;
    const int ngrp = (llen + 15) >> 4;
    const int lsrc = sub * 16;
    for (int grp = bid; grp < ngrp; grp += nb) {
        const int gn = grp * 16 + w * 4 + sub;
        const int j  = (gn < llen) ? list[gn] : -1;
        const int jj = (j < 0) ? 0 : j;

        const float sj = s[jj];
        int deg = (j < 0) ? 0 : cnt[jj];
        if (deg > CAP) deg = CAP;
        const int base = jj * CAP;

        int   sc[4];
        float ev[4];
#pragma unroll
        for (int u = 0; u < 4; ++u) {
            int e = q + u * 16;
            int srcn = 0; float evv = 0.f;
            if (e < deg) {
                srcn = esrc[base + e];
                evv  = expf(leaky(sj + t[srcn]));
            }
            sc[u] = srcn; ev[u] = evv;
        }
        float den = ev[0] + ev[1] + ev[2] + ev[3];
#pragma unroll
        for (int off = 1; off < 16; off <<= 1) den += __shfl_xor(den, off);

        float evs = expf(leaky(sj + t[jj]));
        den += evs;
        float4 hj = cvt4(hb[(size_t)jj * 16 + q]);
        float4 a0, a1, a2, a3;
        a0.x = evs * hj.x; a0.y = evs * hj.y; a0.z = evs * hj.z; a0.w = evs * hj.w;
        a1 = make_float4(0.f, 0.f, 0.f, 0.f);
        a2 = a1; a3 = a1;

#pragma unroll
        for (int u = 0; u < 4; ++u) {
            if (!__any(deg > u * 16)) break;
            ushort4 vb[16];
#pragma unroll
            for (int kk = 0; kk < 16; ++kk) {
                int sK = __shfl(sc[u], lsrc + kk);
                vb[kk] = hb[(size_t)sK * 16 + q];
            }
#define STEP(kk, A) { float eK = __shfl(ev[u], lsrc + kk); \
                      float4 vv = cvt4(vb[kk]); FMA4(A, eK, vv) }
            STEP(0,  a0) STEP(1,  a1) STEP(2,  a2) STEP(3,  a3)
            STEP(4,  a0) STEP(5,  a1) STEP(6,  a2) STEP(7,  a3)
            STEP(8,  a0) STEP(9,  a1) STEP(10, a2) STEP(11, a3)
            STEP(12, a0) STEP(13, a1) STEP(14, a2) STEP(15, a3)
#undef STEP
        }
        float4 acc;
        acc.x = (a0.x + a1.x) + (a2.x + a3.x);
        acc.y = (a0.y + a1.y) + (a2.y + a3.y);
        acc.z = (a0.z + a1.z) + (a2.z + a3.z);
        acc.w = (a0.w + a1.w) + (a2.w + a3.w);

        float4 bv = ((const float4*)bias)[q];
        float inv = 1.0f / (den + 1e-16f);
        float4 v;
        v.x = acc.x * inv + bv.x; v.y = acc.y * inv + bv.y;
        v.z = acc.z * inv + bv.z; v.w = acc.w * inv + bv.w;
        float sq = v.x * v.x + v.y * v.y + v.z * v.z + v.w * v.w;
#pragma unroll
        for (int off = 1; off < 16; off <<= 1) sq += __shfl_xor(sq, off);
        float nm = fmaxf(sqrtf(sq), 1e-12f);
        if (j >= 0) {
            float4 o;
            o.x = v.x / nm; o.y = v.y / nm; o.z = v.z / nm; o.w = v.w / nm;
            g4[(size_t)j * 16 + q] = o;
        }
    }
    __threadfence();
    grid.sync();
    __threadfence();

    // ---------------- P4: scores + reg loss ----------------
    const int gsub = gthr >> 4;          // global 16-lane group id
    const int nsub = nthr >> 4;
    float rgacc = 0.0f;
    for (int b = gsub; b < BB; b += nsub) {
        int u = user[b], p = pos[b], n = neg[b], pr = posr[b], nr = negr[b];
        float4 xu = X4[(size_t)u * 16 + q],  gu = g4[(size_t)u * 16 + q];
        float4 xp = X4[(size_t)p * 16 + q],  gp = g4[(size_t)p * 16 + q];
        float4 xn = X4[(size_t)n * 16 + q],  gn = g4[(size_t)n * 16 + q];
        float4 xq = X4[(size_t)pr * 16 + q], gq = g4[(size_t)pr * 16 + q];
        float4 xm = X4[(size_t)nr * 16 + q], gm = g4[(size_t)nr * 16 + q];
#define DOT(a, c) (a.x * c.x + a.y * c.y + a.z * c.z + a.w * c.w)
        float dp = DOT(xu, xp) + DOT(gu, gp);
        float dn = DOT(xu, xn) + DOT(gu, gn);
        float dq = DOT(xu, xq) + DOT(gu, gq);
        float dm = DOT(xu, xm) + DOT(gu, gm);
        rgacc += 0.5f    * (DOT(xu, xu) + DOT(gu, gu) + DOT(xp, xp) + DOT(gp, gp)
                          + DOT(xn, xn) + DOT(gn, gn))
               + 0.0005f * (DOT(xq, xq) + DOT(gq, gq) + DOT(xm, xm) + DOT(gm, gm));
#undef DOT
#pragma unroll
        for (int off = 1; off < 16; off <<= 1) {
            dp += __shfl_xor(dp, off);
            dn += __shfl_xor(dn, off);
            dq += __shfl_xor(dq, off);
            dm += __shfl_xor(dm, off);
        }
        if (q == 0) {
            out[b]      = dp + 0.1f * dq;
            out[BB + b] = dn + 0.1f * dm;
        }
    }
    // one reg-loss atomic per participating wave
#pragma unroll
    for (int off = 1; off < 64; off <<= 1) rgacc += __shfl_xor(rgacc, off);
    if (lane == 0 && ((gthr >> 6) * 4) < BB) unsafeAtomicAdd(&out[2 * BB], rgacc);
}

extern "C" void kernel_launch(void* const* d_in, const int* in_sizes, int n_in,
                              void* d_out, int out_size, void* d_ws, size_t ws_size,
                              hipStream_t stream) {
    const float4* X4  = (const float4*)d_in[0];
    const float4* W4  = (const float4*)d_in[1];
    const float* att  = (const float*)d_in[2];
    const float* bias = (const float*)d_in[3];
    const int* edges  = (const int*)d_in[4];
    const int* user   = (const int*)d_in[5];
    const int* pos    = (const int*)d_in[6];
    const int* neg    = (const int*)d_in[7];
    const int* posr   = (const int*)d_in[8];
    const int* negr   = (const int*)d_in[9];
    float* out = (float*)d_out;

    // layout: hb | g4 | s | t | cnt | bitmap | listlen | list | esrc
    ushort4*  hb      = (ushort4*)d_ws;                      // NN*16 ushort4 (bf16 h)
    float4*   g4      = (float4*)(hb + (size_t)NN * 16);     // NN*16 float4
    float*    s       = (float*)(g4 + (size_t)NN * 16);      // NN
    float*    t       = s + NN;                              // NN
    int*      cnt     = (int*)(t + NN);                      // NN (lazy-zeroed in P1)
    unsigned* bitmap  = (unsigned*)(cnt + NN);               // BMW
    int*      listlen = (int*)(bitmap + BMW);                // 16 (padded)
    int*      list    = listlen + 16;                        // NLIST
    int*      esrc    = list + NLIST;                        // NN*CAP

    // size the cooperative grid so every block is co-resident
    int maxb = 0;
    hipOccupancyMaxActiveBlocksPerMultiprocessor(&maxb, (const void*)k_mega, 256, 0);
    if (maxb < 1) maxb = 1;
    int ncu = 0;
    hipDeviceGetAttribute(&ncu, hipDeviceAttributeMultiprocessorCount, 0);
    if (ncu < 1) ncu = 256;
    long long gl = (long long)maxb * ncu;
    int gridn = (gl > 2048) ? 2048 : (int)gl;

    void* args[] = { (void*)&X4, (void*)&W4, (void*)&att, (void*)&bias,
                     (void*)&edges, (void*)&user, (void*)&pos, (void*)&neg,
                     (void*)&posr, (void*)&negr,
                     (void*)&hb, (void*)&s, (void*)&t, (void*)&cnt,
                     (void*)&bitmap, (void*)&listlen, (void*)&list,
                     (void*)&esrc, (void*)&g4, (void*)&out };
    hipLaunchCooperativeKernel((void*)k_mega, dim3(gridn), dim3(256), args, 0, stream);
}

// Round 14
// 80.274 us; speedup vs baseline: 4.6420x; 4.6420x over previous
//
#include <hip/hip_runtime.h>

#define NN 100000
#define SE 16
#define NE 1600000        // NN*SE
#define BB 4096
#define CAP 64            // per-node bucket capacity (deg ~ Poisson(16))
#define NMMB 1563         // ceil(NN/64) mm tiles
#define NBUCK 1024        // bucket-role blocks (interleaved, odd bid < 2048)
#define NLIST 20480       // 5*BB upper bound on needed nodes
#define NGB 1280          // NLIST/16 k_gat blocks
#define BMW 3136          // bitmap words (ceil(NN/32)=3125, padded)

__device__ __forceinline__ float leaky(float x) { return x > 0.0f ? x : 0.2f * x; }

__device__ __forceinline__ unsigned short f2bf(float f) {     // RNE f32 -> bf16
    unsigned u = __float_as_uint(f);
    u += 0x7fffu + ((u >> 16) & 1u);
    return (unsigned short)(u >> 16);
}
__device__ __forceinline__ float bf2f(unsigned short h) {
    return __uint_as_float(((unsigned)h) << 16);
}
__device__ __forceinline__ float4 cvt4(ushort4 v) {
    float4 r;
    r.x = bf2f(v.x); r.y = bf2f(v.y); r.z = bf2f(v.z); r.w = bf2f(v.w);
    return r;
}

#define FMA4(a, sx, wv) \
    a.x = fmaf(sx, wv.x, a.x); a.y = fmaf(sx, wv.y, a.y); \
    a.z = fmaf(sx, wv.z, a.z); a.w = fmaf(sx, wv.w, a.w);

// ---------------- zero small state ----------------
__global__ __launch_bounds__(256) void k_zero(unsigned* __restrict__ bitmap,
                                              int* __restrict__ listlen,
                                              float* __restrict__ out) {
    int i = blockIdx.x * 256 + threadIdx.x;
    if (i < BMW) bitmap[i] = 0u;
    if (i < 16) listlen[i] = 0;
    if (i == 0) out[2 * BB] = 0.0f;
}

// ---------------- mark needed nodes, lazy-zero cnt ----------------
__global__ __launch_bounds__(256) void k_mark(const int* __restrict__ user,
                                              const int* __restrict__ pos,
                                              const int* __restrict__ neg,
                                              const int* __restrict__ posr,
                                              const int* __restrict__ negr,
                                              unsigned* __restrict__ bitmap,
                                              int* __restrict__ listlen,
                                              int* __restrict__ list,
                                              int* __restrict__ cnt) {
    int tid = blockIdx.x * 256 + threadIdx.x;   // 80 blocks = 20480 exact
    int a = tid >> 12, e = tid & 4095;
    const int* arr = (a == 0) ? user : (a == 1) ? pos : (a == 2) ? neg
                   : (a == 3) ? posr : negr;
    int node = arr[e];
    unsigned bit = 1u << (node & 31);
    unsigned old = atomicOr(&bitmap[node >> 5], bit);
    if (!(old & bit)) {
        cnt[node] = 0;
        int p = atomicAdd(listlen, 1);
        list[p] = node;
    }
}

// ---------------- fused: h = X@W (bf16 out) + s,t  ||  dst-filtered bucket build ----------------
// Role-split: odd blocks < 2048 stream the edge list (latency-bound, overlaps
// the LDS/VALU-bound mm on the same CUs, m114). 84 VGPR / 33.8 KB LDS -> 4
// blocks/CU: bucket occupancy 37%->~25% standalone-equivalent, mild vs the
// overlap gain (r5's failure mode was 244 VGPR / 10.8% -- not this).
__global__ __launch_bounds__(256) void k_mmb(const float4* __restrict__ X4,
                                             const float4* __restrict__ W4,
                                             const float* __restrict__ att,
                                             const int* __restrict__ edges,
                                             const unsigned* __restrict__ bitmap,
                                             int* __restrict__ cnt,
                                             int* __restrict__ esrc,
                                             ushort4* __restrict__ hb,
                                             float* __restrict__ s,
                                             float* __restrict__ t) {
    __shared__ float4 Wl[64][16];    // Wl[k][q] = W[k][4q..4q+3]
    __shared__ float4 xr[64][17];    // 64 staged rows, padded (2-way conflict = free)
    const int bid = blockIdx.x;
    const int tid = threadIdx.x;

    if ((bid & 1) && bid < 2 * NBUCK) {
        // ---- bucket role ----
        const int bb = bid >> 1;     // 0..NBUCK-1
        for (int e = bb * 256 + tid; e < NE; e += NBUCK * 256) {
            int j = __builtin_nontemporal_load(&edges[e]);
            int i = e >> 4;
            if (j != i && ((bitmap[j >> 5] >> (j & 31)) & 1u)) {
                int p = atomicAdd(&cnt[j], 1);
                if (p < CAP) esrc[j * CAP + p] = i;
            }
        }
        return;
    }

    // ---- mm role: one 64-row tile ----
    const int tile = (bid < 2 * NBUCK) ? (bid >> 1) : (bid - NBUCK);   // 0..NMMB-1
    const int lane = tid & 63;
    const int q    = lane & 15;
    const int slot = ((tid >> 6) << 2) | (lane >> 4);   // 0..15
    const int r0   = tile * 64;

    for (int idx = tid; idx < 1024; idx += 256)
        Wl[idx >> 4][idx & 15] = W4[idx];
#pragma unroll
    for (int u = 0; u < 4; ++u) {
        int idx = u * 256 + tid;
        int row = r0 + (idx >> 4);
        xr[idx >> 4][idx & 15] = (row < NN) ? X4[(size_t)row * 16 + (idx & 15)]
                                            : make_float4(0.f, 0.f, 0.f, 0.f);
    }
    __syncthreads();

    const int rbase = slot * 4;
    float4 acc0 = {0,0,0,0}, acc1 = {0,0,0,0}, acc2 = {0,0,0,0}, acc3 = {0,0,0,0};
#pragma unroll 2
    for (int k4 = 0; k4 < 16; ++k4) {
        float4 w0 = Wl[k4 * 4 + 0][q];
        float4 w1 = Wl[k4 * 4 + 1][q];
        float4 w2 = Wl[k4 * 4 + 2][q];
        float4 w3 = Wl[k4 * 4 + 3][q];
        float4 x0 = xr[rbase + 0][k4];
        float4 x1 = xr[rbase + 1][k4];
        float4 x2 = xr[rbase + 2][k4];
        float4 x3 = xr[rbase + 3][k4];
        FMA4(acc0, x0.x, w0) FMA4(acc0, x0.y, w1) FMA4(acc0, x0.z, w2) FMA4(acc0, x0.w, w3)
        FMA4(acc1, x1.x, w0) FMA4(acc1, x1.y, w1) FMA4(acc1, x1.z, w2) FMA4(acc1, x1.w, w3)
        FMA4(acc2, x2.x, w0) FMA4(acc2, x2.y, w1) FMA4(acc2, x2.z, w2) FMA4(acc2, x2.w, w3)
        FMA4(acc3, x3.x, w0) FMA4(acc3, x3.y, w1) FMA4(acc3, x3.z, w2) FMA4(acc3, x3.w, w3)
    }

    const float4 ai = ((const float4*)att)[q];
    const float4 aj = ((const float4*)att)[16 + q];
    float4 accs[4] = {acc0, acc1, acc2, acc3};
#pragma unroll
    for (int rr = 0; rr < 4; ++rr) {
        int row = r0 + rbase + rr;
        if (row >= NN) continue;
        float4 a = accs[rr];
        ushort4 hv;
        hv.x = f2bf(a.x); hv.y = f2bf(a.y); hv.z = f2bf(a.z); hv.w = f2bf(a.w);
        hb[(size_t)row * 16 + q] = hv;
        float ps = a.x * ai.x + a.y * ai.y + a.z * ai.z + a.w * ai.w;
        float pt = a.x * aj.x + a.y * aj.y + a.z * aj.z + a.w * aj.w;
#pragma unroll
        for (int off = 1; off < 16; off <<= 1) {
            ps += __shfl_xor(ps, off);
            pt += __shfl_xor(pt, off);
        }
        if (q == 0) { s[row] = ps; t[row] = pt; }
    }
}

// ---------------- gather-softmax-aggregate over the NEEDED list only ----------------
__global__ __launch_bounds__(256) void k_gat(const ushort4* __restrict__ hb,
                                             const int* __restrict__ cnt,
                                             const int* __restrict__ esrc,
                                             const float* __restrict__ s,
                                             const float* __restrict__ t,
                                             const float* __restrict__ bias,
                                             const int* __restrict__ listlen,
                                             const int* __restrict__ list,
                                             float4* __restrict__ g4) {
    const int llen = *listlen;
    if (blockIdx.x * 16 >= llen) return;
    const int tid  = threadIdx.x;
    const int lane = tid & 63;
    const int w    = tid >> 6;
    const int q    = lane & 15;
    const int sub  = lane >> 4;
    const int gn   = blockIdx.x * 16 + w * 4 + sub;
    const int j    = (gn < llen) ? list[gn] : -1;
    const int jj   = (j < 0) ? 0 : j;
    const int lsrc = sub * 16;

    const float sj = s[jj];
    int deg = (j < 0) ? 0 : cnt[jj];
    if (deg > CAP) deg = CAP;
    const int base = jj * CAP;

    int   sc[4];
    float ev[4];
#pragma unroll
    for (int u = 0; u < 4; ++u) {
        int e = q + u * 16;
        int srcn = 0; float evv = 0.f;
        if (e < deg) {
            srcn = __builtin_nontemporal_load(&esrc[base + e]);
            evv  = expf(leaky(sj + t[srcn]));
        }
        sc[u] = srcn; ev[u] = evv;
    }
    float den = ev[0] + ev[1] + ev[2] + ev[3];
#pragma unroll
    for (int off = 1; off < 16; off <<= 1) den += __shfl_xor(den, off);

    float evs = expf(leaky(sj + t[jj]));
    den += evs;
    float4 hj = cvt4(hb[(size_t)jj * 16 + q]);
    float4 a0, a1, a2, a3;
    a0.x = evs * hj.x; a0.y = evs * hj.y; a0.z = evs * hj.z; a0.w = evs * hj.w;
    a1 = make_float4(0.f, 0.f, 0.f, 0.f);
    a2 = a1; a3 = a1;

#pragma unroll
    for (int u = 0; u < 4; ++u) {
        if (!__any(deg > u * 16)) break;
        ushort4 vb[16];
#pragma unroll
        for (int kk = 0; kk < 16; ++kk) {
            int sK = __shfl(sc[u], lsrc + kk);
            vb[kk] = hb[(size_t)sK * 16 + q];
        }
#define STEP(kk, A) { float eK = __shfl(ev[u], lsrc + kk); \
                      float4 vv = cvt4(vb[kk]); FMA4(A, eK, vv) }
        STEP(0,  a0) STEP(1,  a1) STEP(2,  a2) STEP(3,  a3)
        STEP(4,  a0) STEP(5,  a1) STEP(6,  a2) STEP(7,  a3)
        STEP(8,  a0) STEP(9,  a1) STEP(10, a2) STEP(11, a3)
        STEP(12, a0) STEP(13, a1) STEP(14, a2) STEP(15, a3)
#undef STEP
    }
    float4 acc;
    acc.x = (a0.x + a1.x) + (a2.x + a3.x);
    acc.y = (a0.y + a1.y) + (a2.y + a3.y);
    acc.z = (a0.z + a1.z) + (a2.z + a3.z);
    acc.w = (a0.w + a1.w) + (a2.w + a3.w);

    float4 bv = ((const float4*)bias)[q];
    float inv = 1.0f / (den + 1e-16f);
    float4 v;
    v.x = acc.x * inv + bv.x; v.y = acc.y * inv + bv.y;
    v.z = acc.z * inv + bv.z; v.w = acc.w * inv + bv.w;
    float sq = v.x * v.x + v.y * v.y + v.z * v.z + v.w * v.w;
#pragma unroll
    for (int off = 1; off < 16; off <<= 1) sq += __shfl_xor(sq, off);
    float nm = fmaxf(sqrtf(sq), 1e-12f);
    if (j >= 0) {
        float4 o;
        o.x = v.x / nm; o.y = v.y / nm; o.z = v.z / nm; o.w = v.w / nm;
        g4[(size_t)j * 16 + q] = o;
    }
}

// ---------------- scores + reg loss ----------------
__global__ __launch_bounds__(256) void k5_score(const float4* __restrict__ X4,
                                                const float4* __restrict__ g4,
                                                const int* __restrict__ user,
                                                const int* __restrict__ pos,
                                                const int* __restrict__ neg,
                                                const int* __restrict__ posr,
                                                const int* __restrict__ negr,
                                                float* __restrict__ out) {
    const int tid  = threadIdx.x;
    const int lane = tid & 63;
    const int q    = lane & 15;
    const int sub  = lane >> 4;
    const int b    = blockIdx.x * 16 + (tid >> 6) * 4 + sub;

    int u = user[b], p = pos[b], n = neg[b], pr = posr[b], nr = negr[b];
    float4 xu = X4[(size_t)u * 16 + q],  gu = g4[(size_t)u * 16 + q];
    float4 xp = X4[(size_t)p * 16 + q],  gp = g4[(size_t)p * 16 + q];
    float4 xn = X4[(size_t)n * 16 + q],  gn = g4[(size_t)n * 16 + q];
    float4 xq = X4[(size_t)pr * 16 + q], gq = g4[(size_t)pr * 16 + q];
    float4 xm = X4[(size_t)nr * 16 + q], gm = g4[(size_t)nr * 16 + q];

#define DOT(a, c) (a.x * c.x + a.y * c.y + a.z * c.z + a.w * c.w)
    float dp = DOT(xu, xp) + DOT(gu, gp);
    float dn = DOT(xu, xn) + DOT(gu, gn);
    float dq = DOT(xu, xq) + DOT(gu, gq);
    float dm = DOT(xu, xm) + DOT(gu, gm);
    float rg = 0.5f    * (DOT(xu, xu) + DOT(gu, gu) + DOT(xp, xp) + DOT(gp, gp)
                        + DOT(xn, xn) + DOT(gn, gn))
             + 0.0005f * (DOT(xq, xq) + DOT(gq, gq) + DOT(xm, xm) + DOT(gm, gm));
#undef DOT
#pragma unroll
    for (int off = 1; off < 16; off <<= 1) {
        dp += __shfl_xor(dp, off);
        dn += __shfl_xor(dn, off);
        dq += __shfl_xor(dq, off);
        dm += __shfl_xor(dm, off);
    }
    if (q == 0) {
        out[b]      = dp + 0.1f * dq;
        out[BB + b] = dn + 0.1f * dm;
    }
#pragma unroll
    for (int off = 16; off < 64; off <<= 1) rg += __shfl_xor(rg, off);
#pragma unroll
    for (int off = 1; off < 16; off <<= 1) rg += __shfl_xor(rg, off);
    if (lane == 0) unsafeAtomicAdd(&out[2 * BB], rg);
}

extern "C" void kernel_launch(void* const* d_in, const int* in_sizes, int n_in,
                              void* d_out, int out_size, void* d_ws, size_t ws_size,
                              hipStream_t stream) {
    const float* X    = (const float*)d_in[0];
    const float* W    = (const float*)d_in[1];
    const float* att  = (const float*)d_in[2];
    const float* bias = (const float*)d_in[3];
    const int* edges  = (const int*)d_in[4];
    const int* user   = (const int*)d_in[5];
    const int* pos    = (const int*)d_in[6];
    const int* neg    = (const int*)d_in[7];
    const int* posr   = (const int*)d_in[8];
    const int* negr   = (const int*)d_in[9];
    float* out = (float*)d_out;

    // layout: hb | g4 | s | t | cnt | bitmap | listlen | list | esrc  (no memsets)
    ushort4*  hb      = (ushort4*)d_ws;                      // NN*16 ushort4 (bf16 h)
    float4*   g4      = (float4*)(hb + (size_t)NN * 16);     // NN*16 float4
    float*    s       = (float*)(g4 + (size_t)NN * 16);      // NN
    float*    t       = s + NN;                              // NN
    int*      cnt     = (int*)(t + NN);                      // NN (lazy-zeroed in k_mark)
    unsigned* bitmap  = (unsigned*)(cnt + NN);               // BMW
    int*      listlen = (int*)(bitmap + BMW);                // 16 (padded)
    int*      list    = listlen + 16;                        // NLIST
    int*      esrc    = list + NLIST;                        // NN*CAP

    k_zero<<<(BMW + 255) / 256, 256, 0, stream>>>(bitmap, listlen, out);
    k_mark<<<80, 256, 0, stream>>>(user, pos, neg, posr, negr, bitmap, listlen, list, cnt);
    k_mmb<<<NMMB + NBUCK, 256, 0, stream>>>((const float4*)X, (const float4*)W, att,
                                            edges, bitmap, cnt, esrc, hb, s, t);
    k_gat<<<NGB, 256, 0, stream>>>(hb, cnt, esrc, s, t, bias, listlen, list, g4);
    k5_score<<<256, 256, 0, stream>>>((const float4*)X, g4, user, pos, neg, posr, negr, out);
}

// Round 15
// 78.113 us; speedup vs baseline: 4.7704x; 1.0277x over previous
//
#include <hip/hip_runtime.h>

#define NN 100000
#define SE 16
#define NE 1600000        // NN*SE
#define BB 4096
#define CAP 64            // per-node bucket capacity (deg ~ Poisson(16))
#define NMMB 1563         // ceil(NN/64) mm tiles
#define NBUCK 1024        // bucket-role blocks (interleaved, odd bid < 2048)
#define NLIST 20480       // 5*BB upper bound on needed nodes
#define NGB 1280          // NLIST/16 k_gat blocks
#define BMW 3136          // bitmap words (ceil(NN/32)=3125, padded)

typedef __attribute__((ext_vector_type(8))) short  bf16x8;   // 8 bf16 = 4 VGPR
typedef __attribute__((ext_vector_type(4))) float  f32x4;

__device__ __forceinline__ float leaky(float x) { return x > 0.0f ? x : 0.2f * x; }

__device__ __forceinline__ unsigned short f2bf(float f) {     // RNE f32 -> bf16
    unsigned u = __float_as_uint(f);
    u += 0x7fffu + ((u >> 16) & 1u);
    return (unsigned short)(u >> 16);
}
__device__ __forceinline__ float bf2f(unsigned short h) {
    return __uint_as_float(((unsigned)h) << 16);
}
__device__ __forceinline__ float4 cvt4(ushort4 v) {
    float4 r;
    r.x = bf2f(v.x); r.y = bf2f(v.y); r.z = bf2f(v.z); r.w = bf2f(v.w);
    return r;
}

#define FMA4(a, sx, wv) \
    a.x = fmaf(sx, wv.x, a.x); a.y = fmaf(sx, wv.y, a.y); \
    a.z = fmaf(sx, wv.z, a.z); a.w = fmaf(sx, wv.w, a.w);

// ---------------- zero small state ----------------
__global__ __launch_bounds__(256) void k_zero(unsigned* __restrict__ bitmap,
                                              int* __restrict__ listlen,
                                              float* __restrict__ out) {
    int i = blockIdx.x * 256 + threadIdx.x;
    if (i < BMW) bitmap[i] = 0u;
    if (i < 16) listlen[i] = 0;
    if (i == 0) out[2 * BB] = 0.0f;
}

// ---------------- mark needed nodes, lazy-zero cnt ----------------
__global__ __launch_bounds__(256) void k_mark(const int* __restrict__ user,
                                              const int* __restrict__ pos,
                                              const int* __restrict__ neg,
                                              const int* __restrict__ posr,
                                              const int* __restrict__ negr,
                                              unsigned* __restrict__ bitmap,
                                              int* __restrict__ listlen,
                                              int* __restrict__ list,
                                              int* __restrict__ cnt) {
    int tid = blockIdx.x * 256 + threadIdx.x;   // 80 blocks = 20480 exact
    int a = tid >> 12, e = tid & 4095;
    const int* arr = (a == 0) ? user : (a == 1) ? pos : (a == 2) ? neg
                   : (a == 3) ? posr : negr;
    int node = arr[e];
    unsigned bit = 1u << (node & 31);
    unsigned old = atomicOr(&bitmap[node >> 5], bit);
    if (!(old & bit)) {
        cnt[node] = 0;
        int p = atomicAdd(listlen, 1);
        list[p] = node;
    }
}

// ---------------- fused: h = X@W via bf16 MFMA + s,t  ||  bucket build ----------------
// mm role: one 64-row tile. X,W staged to LDS as bf16 (convert once at staging);
// Wt transposed [col][k] so B fragments are contiguous ds_read_b128; rows padded
// to 72 elem (144 B stride = 4 banks mod 32 -> 2-way conflict, free). Per wave:
// 16x64 output = 4 col-tiles x 2 K-half mfma_f32_16x16x32_bf16 = 8 MFMAs
// (~40 cyc, replaces 2048 VALU FMA cyc). Fragments: A[l&15][(l>>4)*8+j],
// B[(l>>4)*8+j][l&15], C/D col=l&15,row=(l>>4)*4+reg (m89). C staged via
// wave-private LDS for the bf16-pack + s/t epilogue.
// bucket role (odd bid < 2048): dst-filtered edge scatter, overlaps mm (m114).
__global__ __launch_bounds__(256) void k_mmb(const float4* __restrict__ X4,
                                             const float4* __restrict__ W4,
                                             const float* __restrict__ att,
                                             const int* __restrict__ edges,
                                             const unsigned* __restrict__ bitmap,
                                             int* __restrict__ cnt,
                                             int* __restrict__ esrc,
                                             ushort4* __restrict__ hb,
                                             float* __restrict__ s,
                                             float* __restrict__ t) {
    __shared__ __align__(16) unsigned short Wt[64][72];  // Wt[col][k] bf16
    __shared__ __align__(16) unsigned short Xb[64][72];  // Xb[row][k] bf16
    __shared__ __align__(16) float hs[4][16][68];        // per-wave C staging
    const int bid = blockIdx.x;
    const int tid = threadIdx.x;

    if ((bid & 1) && bid < 2 * NBUCK) {
        // ---- bucket role ----
        const int bb = bid >> 1;     // 0..NBUCK-1
        for (int e = bb * 256 + tid; e < NE; e += NBUCK * 256) {
            int j = __builtin_nontemporal_load(&edges[e]);
            int i = e >> 4;
            if (j != i && ((bitmap[j >> 5] >> (j & 31)) & 1u)) {
                int p = atomicAdd(&cnt[j], 1);
                if (p < CAP) esrc[j * CAP + p] = i;
            }
        }
        return;
    }

    // ---- mm role ----
    const int tile = (bid < 2 * NBUCK) ? (bid >> 1) : (bid - NBUCK);   // 0..NMMB-1
    const int lane = tid & 63;
    const int w    = tid >> 6;
    const int rl   = lane & 15;     // row-in-fragment / col-in-fragment
    const int qt   = lane >> 4;     // lane quarter -> k-block / C row-block
    const int r0   = tile * 64;

    // stage Wt[col][k] (bf16, transposed)
    for (int idx = tid; idx < 1024; idx += 256) {
        int k = idx >> 4, c4 = (idx & 15) * 4;
        float4 wv = W4[idx];
        Wt[c4 + 0][k] = f2bf(wv.x);
        Wt[c4 + 1][k] = f2bf(wv.y);
        Wt[c4 + 2][k] = f2bf(wv.z);
        Wt[c4 + 3][k] = f2bf(wv.w);
    }
    // stage Xb[row][k] (bf16, row-major)
#pragma unroll
    for (int u = 0; u < 4; ++u) {
        int idx = u * 256 + tid;
        int row = idx >> 4, q4 = (idx & 15) * 4;
        int grow = r0 + row;
        float4 xv = (grow < NN) ? X4[(size_t)grow * 16 + (idx & 15)]
                                : make_float4(0.f, 0.f, 0.f, 0.f);
        ushort4 xb;
        xb.x = f2bf(xv.x); xb.y = f2bf(xv.y); xb.z = f2bf(xv.z); xb.w = f2bf(xv.w);
        *(ushort4*)&Xb[row][q4] = xb;
    }
    __syncthreads();

    // A fragments: this wave's rows 16w..16w+15
    const unsigned short* xrow = &Xb[16 * w + rl][0];
    bf16x8 aLo = *(const bf16x8*)(xrow + qt * 8);
    bf16x8 aHi = *(const bf16x8*)(xrow + qt * 8 + 32);

#pragma unroll
    for (int c = 0; c < 4; ++c) {
        const unsigned short* wrow = &Wt[16 * c + rl][0];
        bf16x8 bLo = *(const bf16x8*)(wrow + qt * 8);
        bf16x8 bHi = *(const bf16x8*)(wrow + qt * 8 + 32);
        f32x4 z = {0.f, 0.f, 0.f, 0.f};
        z = __builtin_amdgcn_mfma_f32_16x16x32_bf16(aLo, bLo, z, 0, 0, 0);
        z = __builtin_amdgcn_mfma_f32_16x16x32_bf16(aHi, bHi, z, 0, 0, 0);
#pragma unroll
        for (int r = 0; r < 4; ++r)
            hs[w][qt * 4 + r][16 * c + rl] = z[r];     // C: row=(l>>4)*4+r, col=l&15
    }
    // hs is wave-private: no __syncthreads needed (compiler orders ds via lgkmcnt)

    const float4 ai = ((const float4*)att)[rl];
    const float4 aj = ((const float4*)att)[16 + rl];
#pragma unroll
    for (int rr = 0; rr < 4; ++rr) {
        int lr  = qt * 4 + rr;                // this sub-group's row of the wave tile
        int row = r0 + 16 * w + lr;
        if (row >= NN) continue;
        float4 a = *(const float4*)&hs[w][lr][rl * 4];
        ushort4 hv;
        hv.x = f2bf(a.x); hv.y = f2bf(a.y); hv.z = f2bf(a.z); hv.w = f2bf(a.w);
        hb[(size_t)row * 16 + rl] = hv;
        float ps = a.x * ai.x + a.y * ai.y + a.z * ai.z + a.w * ai.w;
        float pt = a.x * aj.x + a.y * aj.y + a.z * aj.z + a.w * aj.w;
#pragma unroll
        for (int off = 1; off < 16; off <<= 1) {
            ps += __shfl_xor(ps, off);
            pt += __shfl_xor(pt, off);
        }
        if (rl == 0) { s[row] = ps; t[row] = pt; }
    }
}

// ---------------- gather-softmax-aggregate over the NEEDED list only ----------------
__global__ __launch_bounds__(256) void k_gat(const ushort4* __restrict__ hb,
                                             const int* __restrict__ cnt,
                                             const int* __restrict__ esrc,
                                             const float* __restrict__ s,
                                             const float* __restrict__ t,
                                             const float* __restrict__ bias,
                                             const int* __restrict__ listlen,
                                             const int* __restrict__ list,
                                             float4* __restrict__ g4) {
    const int llen = *listlen;
    if (blockIdx.x * 16 >= llen) return;
    const int tid  = threadIdx.x;
    const int lane = tid & 63;
    const int w    = tid >> 6;
    const int q    = lane & 15;
    const int sub  = lane >> 4;
    const int gn   = blockIdx.x * 16 + w * 4 + sub;
    const int j    = (gn < llen) ? list[gn] : -1;
    const int jj   = (j < 0) ? 0 : j;
    const int lsrc = sub * 16;

    const float sj = s[jj];
    int deg = (j < 0) ? 0 : cnt[jj];
    if (deg > CAP) deg = CAP;
    const int base = jj * CAP;

    int   sc[4];
    float ev[4];
#pragma unroll
    for (int u = 0; u < 4; ++u) {
        int e = q + u * 16;
        int srcn = 0; float evv = 0.f;
        if (e < deg) {
            srcn = __builtin_nontemporal_load(&esrc[base + e]);
            evv  = expf(leaky(sj + t[srcn]));
        }
        sc[u] = srcn; ev[u] = evv;
    }
    float den = ev[0] + ev[1] + ev[2] + ev[3];
#pragma unroll
    for (int off = 1; off < 16; off <<= 1) den += __shfl_xor(den, off);

    float evs = expf(leaky(sj + t[jj]));
    den += evs;
    float4 hj = cvt4(hb[(size_t)jj * 16 + q]);
    float4 a0, a1, a2, a3;
    a0.x = evs * hj.x; a0.y = evs * hj.y; a0.z = evs * hj.z; a0.w = evs * hj.w;
    a1 = make_float4(0.f, 0.f, 0.f, 0.f);
    a2 = a1; a3 = a1;

#pragma unroll
    for (int u = 0; u < 4; ++u) {
        if (!__any(deg > u * 16)) break;
        ushort4 vb[16];
#pragma unroll
        for (int kk = 0; kk < 16; ++kk) {
            int sK = __shfl(sc[u], lsrc + kk);
            vb[kk] = hb[(size_t)sK * 16 + q];
        }
#define STEP(kk, A) { float eK = __shfl(ev[u], lsrc + kk); \
                      float4 vv = cvt4(vb[kk]); FMA4(A, eK, vv) }
        STEP(0,  a0) STEP(1,  a1) STEP(2,  a2) STEP(3,  a3)
        STEP(4,  a0) STEP(5,  a1) STEP(6,  a2) STEP(7,  a3)
        STEP(8,  a0) STEP(9,  a1) STEP(10, a2) STEP(11, a3)
        STEP(12, a0) STEP(13, a1) STEP(14, a2) STEP(15, a3)
#undef STEP
    }
    float4 acc;
    acc.x = (a0.x + a1.x) + (a2.x + a3.x);
    acc.y = (a0.y + a1.y) + (a2.y + a3.y);
    acc.z = (a0.z + a1.z) + (a2.z + a3.z);
    acc.w = (a0.w + a1.w) + (a2.w + a3.w);

    float4 bv = ((const float4*)bias)[q];
    float inv = 1.0f / (den + 1e-16f);
    float4 v;
    v.x = acc.x * inv + bv.x; v.y = acc.y * inv + bv.y;
    v.z = acc.z * inv + bv.z; v.w = acc.w * inv + bv.w;
    float sq = v.x * v.x + v.y * v.y + v.z * v.z + v.w * v.w;
#pragma unroll
    for (int off = 1; off < 16; off <<= 1) sq += __shfl_xor(sq, off);
    float nm = fmaxf(sqrtf(sq), 1e-12f);
    if (j >= 0) {
        float4 o;
        o.x = v.x / nm; o.y = v.y / nm; o.z = v.z / nm; o.w = v.w / nm;
        g4[(size_t)j * 16 + q] = o;
    }
}

// ---------------- scores + reg loss ----------------
__global__ __launch_bounds__(256) void k5_score(const float4* __restrict__ X4,
                                                const float4* __restrict__ g4,
                                                const int* __restrict__ user,
                                                const int* __restrict__ pos,
                                                const int* __restrict__ neg,
                                                const int* __restrict__ posr,
                                                const int* __restrict__ negr,
                                                float* __restrict__ out) {
    const int tid  = threadIdx.x;
    const int lane = tid & 63;
    const int q    = lane & 15;
    const int sub  = lane >> 4;
    const int b    = blockIdx.x * 16 + (tid >> 6) * 4 + sub;

    int u = user[b], p = pos[b], n = neg[b], pr = posr[b], nr = negr[b];
    float4 xu = X4[(size_t)u * 16 + q],  gu = g4[(size_t)u * 16 + q];
    float4 xp = X4[(size_t)p * 16 + q],  gp = g4[(size_t)p * 16 + q];
    float4 xn = X4[(size_t)n * 16 + q],  gn = g4[(size_t)n * 16 + q];
    float4 xq = X4[(size_t)pr * 16 + q], gq = g4[(size_t)pr * 16 + q];
    float4 xm = X4[(size_t)nr * 16 + q], gm = g4[(size_t)nr * 16 + q];

#define DOT(a, c) (a.x * c.x + a.y * c.y + a.z * c.z + a.w * c.w)
    float dp = DOT(xu, xp) + DOT(gu, gp);
    float dn = DOT(xu, xn) + DOT(gu, gn);
    float dq = DOT(xu, xq) + DOT(gu, gq);
    float dm = DOT(xu, xm) + DOT(gu, gm);
    float rg = 0.5f    * (DOT(xu, xu) + DOT(gu, gu) + DOT(xp, xp) + DOT(gp, gp)
                        + DOT(xn, xn) + DOT(gn, gn))
             + 0.0005f * (DOT(xq, xq) + DOT(gq, gq) + DOT(xm, xm) + DOT(gm, gm));
#undef DOT
#pragma unroll
    for (int off = 1; off < 16; off <<= 1) {
        dp += __shfl_xor(dp, off);
        dn += __shfl_xor(dn, off);
        dq += __shfl_xor(dq, off);
        dm += __shfl_xor(dm, off);
    }
    if (q == 0) {
        out[b]      = dp + 0.1f * dq;
        out[BB + b] = dn + 0.1f * dm;
    }
#pragma unroll
    for (int off = 16; off < 64; off <<= 1) rg += __shfl_xor(rg, off);
#pragma unroll
    for (int off = 1; off < 16; off <<= 1) rg += __shfl_xor(rg, off);
    if (lane == 0) unsafeAtomicAdd(&out[2 * BB], rg);
}

extern "C" void kernel_launch(void* const* d_in, const int* in_sizes, int n_in,
                              void* d_out, int out_size, void* d_ws, size_t ws_size,
                              hipStream_t stream) {
    const float* X    = (const float*)d_in[0];
    const float* W    = (const float*)d_in[1];
    const float* att  = (const float*)d_in[2];
    const float* bias = (const float*)d_in[3];
    const int* edges  = (const int*)d_in[4];
    const int* user   = (const int*)d_in[5];
    const int* pos    = (const int*)d_in[6];
    const int* neg    = (const int*)d_in[7];
    const int* posr   = (const int*)d_in[8];
    const int* negr   = (const int*)d_in[9];
    float* out = (float*)d_out;

    // layout: hb | g4 | s | t | cnt | bitmap | listlen | list | esrc  (no memsets)
    ushort4*  hb      = (ushort4*)d_ws;                      // NN*16 ushort4 (bf16 h)
    float4*   g4      = (float4*)(hb + (size_t)NN * 16);     // NN*16 float4
    float*    s       = (float*)(g4 + (size_t)NN * 16);      // NN
    float*    t       = s + NN;                              // NN
    int*      cnt     = (int*)(t + NN);                      // NN (lazy-zeroed in k_mark)
    unsigned* bitmap  = (unsigned*)(cnt + NN);               // BMW
    int*      listlen = (int*)(bitmap + BMW);                // 16 (padded)
    int*      list    = listlen + 16;                        // NLIST
    int*      esrc    = list + NLIST;                        // NN*CAP

    k_zero<<<(BMW + 255) / 256, 256, 0, stream>>>(bitmap, listlen, out);
    k_mark<<<80, 256, 0, stream>>>(user, pos, neg, posr, negr, bitmap, listlen, list, cnt);
    k_mmb<<<NMMB + NBUCK, 256, 0, stream>>>((const float4*)X, (const float4*)W, att,
                                            edges, bitmap, cnt, esrc, hb, s, t);
    k_gat<<<NGB, 256, 0, stream>>>(hb, cnt, esrc, s, t, bias, listlen, list, g4);
    k5_score<<<256, 256, 0, stream>>>((const float4*)X, g4, user, pos, neg, posr, negr, out);
}

// Round 17
// 74.183 us; speedup vs baseline: 5.0231x; 1.0530x over previous
//
#include <hip/hip_runtime.h>

#define NN 100000
#define SE 16
#define NE 1600000        // NN*SE
#define NE4 400000        // NE/4 int4 edge loads
#define BB 4096
#define CAP 64            // per-node bucket capacity (deg ~ Poisson(16))
#define NMMB 1563         // ceil(NN/64) mm tiles
#define NBUCK 1024        // bucket-role blocks (interleaved, odd bid < 2048)
#define NLIST 20480       // 5*BB upper bound on needed nodes
#define NGB 1280          // NLIST/16 k_gat blocks
#define BMW 3136          // bitmap words (ceil(NN/32)=3125, padded)

typedef __attribute__((ext_vector_type(8))) short  bf16x8;   // 8 bf16 = 4 VGPR
typedef __attribute__((ext_vector_type(4))) float  f32x4;
typedef __attribute__((ext_vector_type(4))) int    vi4;      // nontemporal-legal int4

__device__ __forceinline__ float leaky(float x) { return x > 0.0f ? x : 0.2f * x; }

__device__ __forceinline__ unsigned short f2bf(float f) {     // RNE f32 -> bf16
    unsigned u = __float_as_uint(f);
    u += 0x7fffu + ((u >> 16) & 1u);
    return (unsigned short)(u >> 16);
}
__device__ __forceinline__ float bf2f(unsigned short h) {
    return __uint_as_float(((unsigned)h) << 16);
}
__device__ __forceinline__ float4 cvt4(ushort4 v) {
    float4 r;
    r.x = bf2f(v.x); r.y = bf2f(v.y); r.z = bf2f(v.z); r.w = bf2f(v.w);
    return r;
}

#define FMA4(a, sx, wv) \
    a.x = fmaf(sx, wv.x, a.x); a.y = fmaf(sx, wv.y, a.y); \
    a.z = fmaf(sx, wv.z, a.z); a.w = fmaf(sx, wv.w, a.w);

// ---------------- zero small state ----------------
__global__ __launch_bounds__(256) void k_zero(unsigned* __restrict__ bitmap,
                                              int* __restrict__ listlen,
                                              float* __restrict__ out) {
    int i = blockIdx.x * 256 + threadIdx.x;
    if (i < BMW) bitmap[i] = 0u;
    if (i < 16) listlen[i] = 0;
    if (i == 0) out[2 * BB] = 0.0f;
}

// ---------------- mark needed nodes, lazy-zero cnt ----------------
__global__ __launch_bounds__(256) void k_mark(const int* __restrict__ user,
                                              const int* __restrict__ pos,
                                              const int* __restrict__ neg,
                                              const int* __restrict__ posr,
                                              const int* __restrict__ negr,
                                              unsigned* __restrict__ bitmap,
                                              int* __restrict__ listlen,
                                              int* __restrict__ list,
                                              int* __restrict__ cnt) {
    int tid = blockIdx.x * 256 + threadIdx.x;   // 80 blocks = 20480 exact
    int a = tid >> 12, e = tid & 4095;
    const int* arr = (a == 0) ? user : (a == 1) ? pos : (a == 2) ? neg
                   : (a == 3) ? posr : negr;
    int node = arr[e];
    unsigned bit = 1u << (node & 31);
    unsigned old = atomicOr(&bitmap[node >> 5], bit);
    if (!(old & bit)) {
        cnt[node] = 0;
        int p = atomicAdd(listlen, 1);
        list[p] = node;
    }
}

// ---------------- fused: h = X@W via bf16 MFMA + s,t  ||  bucket build ----------------
// mm role: one 64-row tile. X,W staged to LDS as bf16; Wt transposed [col][k]
// (72-elem rows: 2-way bank conflict, free). Per wave: 4 col-tiles x 2 K-half
// mfma_f32_16x16x32_bf16. Per c-tile the C fragment (col=rl, rows qt*4+r) is
// transposed through a per-wave 16x20 LDS buffer to (row=rl, cols 4qt..4qt+3),
// written as that hb quarter, and dotted with the att quarters (s/t partials
// reduced over qt at the end). LDS 23.5 KB -> 6 blocks/CU (was 35.8/4).
// bucket role (odd bid < 2048): dst-filtered edge scatter with vi4 edge loads
// (1.5 grid-stride iters vs 6.1 scalar); overlaps mm on the same CUs (m114).
__global__ __launch_bounds__(256) void k_mmb(const float4* __restrict__ X4,
                                             const float4* __restrict__ W4,
                                             const float* __restrict__ att,
                                             const int* __restrict__ edges,
                                             const unsigned* __restrict__ bitmap,
                                             int* __restrict__ cnt,
                                             int* __restrict__ esrc,
                                             ushort4* __restrict__ hb,
                                             float* __restrict__ s,
                                             float* __restrict__ t) {
    __shared__ __align__(16) unsigned short Wt[64][72];  // Wt[col][k] bf16
    __shared__ __align__(16) unsigned short Xb[64][72];  // Xb[row][k] bf16
    __shared__ __align__(16) float ws4[4][16][20];       // per-wave c-tile transpose
    const int bid = blockIdx.x;
    const int tid = threadIdx.x;

    if ((bid & 1) && bid < 2 * NBUCK) {
        // ---- bucket role: 16B vector edge stream ----
        const int bb = bid >> 1;     // 0..NBUCK-1
        const vi4* e4 = (const vi4*)edges;
        for (int e = bb * 256 + tid; e < NE4; e += NBUCK * 256) {
            vi4 v = __builtin_nontemporal_load(&e4[e]);
            int eb = e * 4;
#define PUSH(jv, ee) { int j = (jv); int i = (ee) >> 4; \
            if (j != i && ((bitmap[j >> 5] >> (j & 31)) & 1u)) { \
                int p = atomicAdd(&cnt[j], 1); \
                if (p < CAP) esrc[j * CAP + p] = i; } }
            PUSH(v.x, eb + 0)
            PUSH(v.y, eb + 1)
            PUSH(v.z, eb + 2)
            PUSH(v.w, eb + 3)
#undef PUSH
        }
        return;
    }

    // ---- mm role ----
    const int tile = (bid < 2 * NBUCK) ? (bid >> 1) : (bid - NBUCK);   // 0..NMMB-1
    const int lane = tid & 63;
    const int w    = tid >> 6;
    const int rl   = lane & 15;     // A row / B col within fragment
    const int qt   = lane >> 4;     // lane quarter -> k-block / C row-block
    const int r0   = tile * 64;

    // stage Wt[col][k] (bf16, transposed)
    for (int idx = tid; idx < 1024; idx += 256) {
        int k = idx >> 4, c4 = (idx & 15) * 4;
        float4 wv = W4[idx];
        Wt[c4 + 0][k] = f2bf(wv.x);
        Wt[c4 + 1][k] = f2bf(wv.y);
        Wt[c4 + 2][k] = f2bf(wv.z);
        Wt[c4 + 3][k] = f2bf(wv.w);
    }
    // stage Xb[row][k] (bf16, row-major)
#pragma unroll
    for (int u = 0; u < 4; ++u) {
        int idx = u * 256 + tid;
        int row = idx >> 4, q4 = (idx & 15) * 4;
        int grow = r0 + row;
        float4 xv = (grow < NN) ? X4[(size_t)grow * 16 + (idx & 15)]
                                : make_float4(0.f, 0.f, 0.f, 0.f);
        ushort4 xb;
        xb.x = f2bf(xv.x); xb.y = f2bf(xv.y); xb.z = f2bf(xv.z); xb.w = f2bf(xv.w);
        *(ushort4*)&Xb[row][q4] = xb;
    }
    __syncthreads();

    // A fragments: this wave's rows 16w..16w+15
    const unsigned short* xrow = &Xb[16 * w + rl][0];
    bf16x8 aLo = *(const bf16x8*)(xrow + qt * 8);
    bf16x8 aHi = *(const bf16x8*)(xrow + qt * 8 + 32);

    const int myrow = r0 + 16 * w + rl;           // row this lane owns in epilogue
    float ps = 0.f, pt = 0.f;

#pragma unroll
    for (int c = 0; c < 4; ++c) {
        const unsigned short* wrow = &Wt[16 * c + rl][0];
        bf16x8 bLo = *(const bf16x8*)(wrow + qt * 8);
        bf16x8 bHi = *(const bf16x8*)(wrow + qt * 8 + 32);
        f32x4 z = {0.f, 0.f, 0.f, 0.f};
        z = __builtin_amdgcn_mfma_f32_16x16x32_bf16(aLo, bLo, z, 0, 0, 0);
        z = __builtin_amdgcn_mfma_f32_16x16x32_bf16(aHi, bHi, z, 0, 0, 0);
        // transpose within wave via per-wave LDS (same-wave ds order, r15-verified)
#pragma unroll
        for (int r = 0; r < 4; ++r)
            ws4[w][qt * 4 + r][rl] = z[r];        // [row][col-in-tile]
        float4 a = *(const float4*)&ws4[w][rl][qt * 4];   // row rl, cols 16c+4qt..+3
        if (myrow < NN) {
            ushort4 hv;
            hv.x = f2bf(a.x); hv.y = f2bf(a.y); hv.z = f2bf(a.z); hv.w = f2bf(a.w);
            hb[(size_t)myrow * 16 + 4 * c + qt] = hv;
        }
        float4 aiq = ((const float4*)att)[4 * c + qt];
        float4 ajq = ((const float4*)att)[16 + 4 * c + qt];
        ps += a.x * aiq.x + a.y * aiq.y + a.z * aiq.z + a.w * aiq.w;
        pt += a.x * ajq.x + a.y * ajq.y + a.z * ajq.z + a.w * ajq.w;
    }
    // reduce partials over the 4 qt lanes sharing rl
    ps += __shfl_xor(ps, 16); ps += __shfl_xor(ps, 32);
    pt += __shfl_xor(pt, 16); pt += __shfl_xor(pt, 32);
    if (qt == 0 && myrow < NN) { s[myrow] = ps; t[myrow] = pt; }
}

// ---------------- gather-softmax-aggregate over the NEEDED list only ----------------
__global__ __launch_bounds__(256) void k_gat(const ushort4* __restrict__ hb,
                                             const int* __restrict__ cnt,
                                             const int* __restrict__ esrc,
                                             const float* __restrict__ s,
                                             const float* __restrict__ t,
                                             const float* __restrict__ bias,
                                             const int* __restrict__ listlen,
                                             const int* __restrict__ list,
                                             float4* __restrict__ g4) {
    const int llen = *listlen;
    if (blockIdx.x * 16 >= llen) return;
    const int tid  = threadIdx.x;
    const int lane = tid & 63;
    const int w    = tid >> 6;
    const int q    = lane & 15;
    const int sub  = lane >> 4;
    const int gn   = blockIdx.x * 16 + w * 4 + sub;
    const int j    = (gn < llen) ? list[gn] : -1;
    const int jj   = (j < 0) ? 0 : j;
    const int lsrc = sub * 16;

    const float sj = s[jj];
    int deg = (j < 0) ? 0 : cnt[jj];
    if (deg > CAP) deg = CAP;
    const int base = jj * CAP;

    int   sc[4];
    float ev[4];
#pragma unroll
    for (int u = 0; u < 4; ++u) {
        int e = q + u * 16;
        int srcn = 0; float evv = 0.f;
        if (e < deg) {
            srcn = __builtin_nontemporal_load(&esrc[base + e]);
            evv  = expf(leaky(sj + t[srcn]));
        }
        sc[u] = srcn; ev[u] = evv;
    }
    float den = ev[0] + ev[1] + ev[2] + ev[3];
#pragma unroll
    for (int off = 1; off < 16; off <<= 1) den += __shfl_xor(den, off);

    float evs = expf(leaky(sj + t[jj]));
    den += evs;
    float4 hj = cvt4(hb[(size_t)jj * 16 + q]);
    float4 a0, a1, a2, a3;
    a0.x = evs * hj.x; a0.y = evs * hj.y; a0.z = evs * hj.z; a0.w = evs * hj.w;
    a1 = make_float4(0.f, 0.f, 0.f, 0.f);
    a2 = a1; a3 = a1;

#pragma unroll
    for (int u = 0; u < 4; ++u) {
        if (!__any(deg > u * 16)) break;
        ushort4 vb[16];
#pragma unroll
        for (int kk = 0; kk < 16; ++kk) {
            int sK = __shfl(sc[u], lsrc + kk);
            vb[kk] = hb[(size_t)sK * 16 + q];
        }
#define STEP(kk, A) { float eK = __shfl(ev[u], lsrc + kk); \
                      float4 vv = cvt4(vb[kk]); FMA4(A, eK, vv) }
        STEP(0,  a0) STEP(1,  a1) STEP(2,  a2) STEP(3,  a3)
        STEP(4,  a0) STEP(5,  a1) STEP(6,  a2) STEP(7,  a3)
        STEP(8,  a0) STEP(9,  a1) STEP(10, a2) STEP(11, a3)
        STEP(12, a0) STEP(13, a1) STEP(14, a2) STEP(15, a3)
#undef STEP
    }
    float4 acc;
    acc.x = (a0.x + a1.x) + (a2.x + a3.x);
    acc.y = (a0.y + a1.y) + (a2.y + a3.y);
    acc.z = (a0.z + a1.z) + (a2.z + a3.z);
    acc.w = (a0.w + a1.w) + (a2.w + a3.w);

    float4 bv = ((const float4*)bias)[q];
    float inv = 1.0f / (den + 1e-16f);
    float4 v;
    v.x = acc.x * inv + bv.x; v.y = acc.y * inv + bv.y;
    v.z = acc.z * inv + bv.z; v.w = acc.w * inv + bv.w;
    float sq = v.x * v.x + v.y * v.y + v.z * v.z + v.w * v.w;
#pragma unroll
    for (int off = 1; off < 16; off <<= 1) sq += __shfl_xor(sq, off);
    float nm = fmaxf(sqrtf(sq), 1e-12f);
    if (j >= 0) {
        float4 o;
        o.x = v.x / nm; o.y = v.y / nm; o.z = v.z / nm; o.w = v.w / nm;
        g4[(size_t)j * 16 + q] = o;
    }
}

// ---------------- scores + reg loss ----------------
__global__ __launch_bounds__(256) void k5_score(const float4* __restrict__ X4,
                                                const float4* __restrict__ g4,
                                                const int* __restrict__ user,
                                                const int* __restrict__ pos,
                                                const int* __restrict__ neg,
                                                const int* __restrict__ posr,
                                                const int* __restrict__ negr,
                                                float* __restrict__ out) {
    const int tid  = threadIdx.x;
    const int lane = tid & 63;
    const int q    = lane & 15;
    const int sub  = lane >> 4;
    const int b    = blockIdx.x * 16 + (tid >> 6) * 4 + sub;

    int u = user[b], p = pos[b], n = neg[b], pr = posr[b], nr = negr[b];
    float4 xu = X4[(size_t)u * 16 + q],  gu = g4[(size_t)u * 16 + q];
    float4 xp = X4[(size_t)p * 16 + q],  gp = g4[(size_t)p * 16 + q];
    float4 xn = X4[(size_t)n * 16 + q],  gn = g4[(size_t)n * 16 + q];
    float4 xq = X4[(size_t)pr * 16 + q], gq = g4[(size_t)pr * 16 + q];
    float4 xm = X4[(size_t)nr * 16 + q], gm = g4[(size_t)nr * 16 + q];

#define DOT(a, c) (a.x * c.x + a.y * c.y + a.z * c.z + a.w * c.w)
    float dp = DOT(xu, xp) + DOT(gu, gp);
    float dn = DOT(xu, xn) + DOT(gu, gn);
    float dq = DOT(xu, xq) + DOT(gu, gq);
    float dm = DOT(xu, xm) + DOT(gu, gm);
    float rg = 0.5f    * (DOT(xu, xu) + DOT(gu, gu) + DOT(xp, xp) + DOT(gp, gp)
                        + DOT(xn, xn) + DOT(gn, gn))
             + 0.0005f * (DOT(xq, xq) + DOT(gq, gq) + DOT(xm, xm) + DOT(gm, gm));
#undef DOT
#pragma unroll
    for (int off = 1; off < 16; off <<= 1) {
        dp += __shfl_xor(dp, off);
        dn += __shfl_xor(dn, off);
        dq += __shfl_xor(dq, off);
        dm += __shfl_xor(dm, off);
    }
    if (q == 0) {
        out[b]      = dp + 0.1f * dq;
        out[BB + b] = dn + 0.1f * dm;
    }
#pragma unroll
    for (int off = 16; off < 64; off <<= 1) rg += __shfl_xor(rg, off);
#pragma unroll
    for (int off = 1; off < 16; off <<= 1) rg += __shfl_xor(rg, off);
    if (lane == 0) unsafeAtomicAdd(&out[2 * BB], rg);
}

extern "C" void kernel_launch(void* const* d_in, const int* in_sizes, int n_in,
                              void* d_out, int out_size, void* d_ws, size_t ws_size,
                              hipStream_t stream) {
    const float* X    = (const float*)d_in[0];
    const float* W    = (const float*)d_in[1];
    const float* att  = (const float*)d_in[2];
    const float* bias = (const float*)d_in[3];
    const int* edges  = (const int*)d_in[4];
    const int* user   = (const int*)d_in[5];
    const int* pos    = (const int*)d_in[6];
    const int* neg    = (const int*)d_in[7];
    const int* posr   = (const int*)d_in[8];
    const int* negr   = (const int*)d_in[9];
    float* out = (float*)d_out;

    // layout: hb | g4 | s | t | cnt | bitmap | listlen | list | esrc  (no memsets)
    ushort4*  hb      = (ushort4*)d_ws;                      // NN*16 ushort4 (bf16 h)
    float4*   g4      = (float4*)(hb + (size_t)NN * 16);     // NN*16 float4
    float*    s       = (float*)(g4 + (size_t)NN * 16);      // NN
    float*    t       = s + NN;                              // NN
    int*      cnt     = (int*)(t + NN);                      // NN (lazy-zeroed in k_mark)
    unsigned* bitmap  = (unsigned*)(cnt + NN);               // BMW
    int*      listlen = (int*)(bitmap + BMW);                // 16 (padded)
    int*      list    = listlen + 16;                        // NLIST
    int*      esrc    = list + NLIST;                        // NN*CAP

    k_zero<<<(BMW + 255) / 256, 256, 0, stream>>>(bitmap, listlen, out);
    k_mark<<<80, 256, 0, stream>>>(user, pos, neg, posr, negr, bitmap, listlen, list, cnt);
    k_mmb<<<NMMB + NBUCK, 256, 0, stream>>>((const float4*)X, (const float4*)W, att,
                                            edges, bitmap, cnt, esrc, hb, s, t);
    k_gat<<<NGB, 256, 0, stream>>>(hb, cnt, esrc, s, t, bias, listlen, list, g4);
    k5_score<<<256, 256, 0, stream>>>((const float4*)X, g4, user, pos, neg, posr, negr, out);
}